// Round 3
// baseline (576.140 us; speedup 1.0000x reference)
//
#include <hip/hip_runtime.h>

#define N_NODES 8192
#define IN_F 256
#define OUT_F 128
#define ALPHA 0.5f
#define JC 4
#define KCHUNK 2048            // N_NODES / JC
#define STEPS (KCHUNK/32)      // 64 32-k MFMA steps per chunk

using short8 = __attribute__((ext_vector_type(8))) short;
using f32x4  = __attribute__((ext_vector_type(4))) float;

__device__ __forceinline__ unsigned int f2bf(float f){
  unsigned int u = __float_as_uint(f);
  u += 0x7fffu + ((u >> 16) & 1u);   // RNE
  return u >> 16;
}
__device__ __forceinline__ float bf2f(short s){
  return __uint_as_float(((unsigned int)(unsigned short)s) << 16);
}

// ---------------- K0: fused  h = x@W  ->  {f1, f2, P(bf16 frag-major)} -----
// h is never written to global: f1/f2 reduced from fp32 accumulators,
// bf16 pack done via LDS re-stage (reusing the x staging buffer).
__global__ __launch_bounds__(256) void k_hfp(const float* __restrict__ x,
                                             const float* __restrict__ W,
                                             const float* __restrict__ a,
                                             unsigned short* __restrict__ P,
                                             float* __restrict__ f1,
                                             float* __restrict__ f2){
  __shared__ float xs[16*IN_F];            // 16 KB; reused as hs[16][132]
  const int tid = threadIdx.x;
  const int bx = blockIdx.x;
  const int r0 = bx * 16;
  const float4* xg = (const float4*)(x + (size_t)r0*IN_F);
  float4* xl = (float4*)xs;
  #pragma unroll
  for(int i=0;i<4;i++) xl[tid + i*256] = xg[tid + i*256];
  __syncthreads();
  const int wave = tid >> 6, lane = tid & 63;
  float2 acc[4];
  #pragma unroll
  for(int j=0;j<4;j++){ acc[j].x = 0.f; acc[j].y = 0.f; }
  const float2* Wp = (const float2*)W;
  for(int k4=0;k4<IN_F;k4+=4){
    float4 xq[4];
    #pragma unroll
    for(int j=0;j<4;j++) xq[j] = *(const float4*)&xs[(wave*4+j)*IN_F + k4];
    #pragma unroll
    for(int kk=0;kk<4;kk++){
      float2 wv = Wp[(size_t)(k4+kk)*64 + lane];
      #pragma unroll
      for(int j=0;j<4;j++){
        float xv = kk==0?xq[j].x : kk==1?xq[j].y : kk==2?xq[j].z : xq[j].w;
        acc[j].x += xv*wv.x; acc[j].y += xv*wv.y;
      }
    }
  }
  // ---- f1 = h@a1, f2 = h@a2 from fp32 accumulators ----
  float2 av1 = ((const float2*)a)[lane];
  float2 av2 = ((const float2*)(a + OUT_F))[lane];
  #pragma unroll
  for(int j=0;j<4;j++){
    float s1 = acc[j].x*av1.x + acc[j].y*av1.y;
    float s2 = acc[j].x*av2.x + acc[j].y*av2.y;
    #pragma unroll
    for(int off=32; off; off>>=1){
      s1 += __shfl_down(s1, off);
      s2 += __shfl_down(s2, off);
    }
    if(lane == 0){ f1[r0 + wave*4 + j] = s1; f2[r0 + wave*4 + j] = s2; }
  }
  // ---- pack bf16 fragment-major into P via LDS re-stage ----
  // P short idx ((kb*8+c)*64 + q*16 + n)*8 + t = bf16(h[kb*32+q*8+t][c*16+n])
  __syncthreads();                         // all waves done reading xs
  #pragma unroll
  for(int j=0;j<4;j++) *(float2*)&xs[(wave*4+j)*132 + lane*2] = acc[j];
  __syncthreads();
  const int kb = bx >> 1, half = bx & 1;   // this block = rows [r0, r0+16) = half of kb's 32
  const int c = tid >> 5, ql = (tid >> 4) & 1, n = tid & 15;
  short8 v;
  #pragma unroll
  for(int t=0;t<8;t++) v[t] = (short)f2bf(xs[(ql*8+t)*132 + c*16 + n]);
  *(short8*)(P + ((size_t)((kb*8 + c)*64 + half*32 + ql*16 + n))*8) = v;
}

// ---------------- K1: barrier-free fused masked-exp + attn@h --------------
// No LDS, no __syncthreads in the loop. Each wave owns 16 rows; lane
// (q*16+m) builds its A-fragment A[m][q*8+t] in registers from 2 coalesced
// int4 adj loads, B-fragments load directly from fragment-major P (L2-
// resident: each XCD serves exactly one jc chunk). 1-step register
// prefetch keeps the adj HBM stream permanently in flight — nothing ever
// issues a vmcnt(0) drain.
__global__ __launch_bounds__(256, 2) void k_attn(const int* __restrict__ adj,
    const unsigned short* __restrict__ P,
    const float* __restrict__ f1, const float* __restrict__ f2,
    float* __restrict__ part, float* __restrict__ denp){
  const int tid = threadIdx.x;
  const int wave = tid >> 6, lane = tid & 63;
  const int m = lane & 15, q = lane >> 4;
  const int jc = blockIdx.x;                 // linear id % 4 -> one jc per XCD
  const int r0w = blockIdx.y * 64 + wave*16; // this wave's 16 rows
  const int jb = jc * KCHUNK;
  const int kb0 = jc * STEPS;                // P 32-k block base

  const float f1v = f1[r0w + m];             // constant for whole kernel
  f32x4 acc[8];
  #pragma unroll
  for(int c=0;c<8;c++) acc[c] = (f32x4){0,0,0,0};
  float den = 0.f;

  const char* aprow = (const char*)adj + ((size_t)(r0w + m)*N_NODES + jb + q*8)*4;
  const float* f2p = f2 + jb + q*8;
  const short8* P8 = (const short8*)P;

  // prologue: step-0 adj + f2 in regs
  int4 a0 = *(const int4*)(aprow);
  int4 a1 = *(const int4*)(aprow + 16);
  float4 g0 = *(const float4*)(f2p);
  float4 g1 = *(const float4*)(f2p + 4);

  for(int s=0; s<STEPS; s++){
    // ---- B-frags for this step (8 x 1KB-coalesced dwordx4 from L2) ----
    const short8* Bs = P8 + ((size_t)(kb0 + s)*8)*64 + lane;
    short8 bf[8];
    #pragma unroll
    for(int c=0;c<8;c++) bf[c] = Bs[c*64];
    // ---- prefetch next step's adj + f2 (stays in flight through MFMA) ----
    const int sn = (s+1 < STEPS) ? s+1 : s;
    int4 na0 = *(const int4*)(aprow + (size_t)sn*128);
    int4 na1 = *(const int4*)(aprow + (size_t)sn*128 + 16);
    float4 ng0 = *(const float4*)(f2p + sn*32);
    float4 ng1 = *(const float4*)(f2p + sn*32 + 4);
    // ---- A-frag: w = mask * exp(leakyrelu(f1+f2)) for 8 k's of row m ----
    float e0 = f1v + g0.x; e0 = e0>0.f?e0:ALPHA*e0; float w0 = a0.x>0?__expf(e0):0.f;
    float e1 = f1v + g0.y; e1 = e1>0.f?e1:ALPHA*e1; float w1 = a0.y>0?__expf(e1):0.f;
    float e2 = f1v + g0.z; e2 = e2>0.f?e2:ALPHA*e2; float w2 = a0.z>0?__expf(e2):0.f;
    float e3 = f1v + g0.w; e3 = e3>0.f?e3:ALPHA*e3; float w3 = a0.w>0?__expf(e3):0.f;
    float e4 = f1v + g1.x; e4 = e4>0.f?e4:ALPHA*e4; float w4 = a1.x>0?__expf(e4):0.f;
    float e5 = f1v + g1.y; e5 = e5>0.f?e5:ALPHA*e5; float w5 = a1.y>0?__expf(e5):0.f;
    float e6 = f1v + g1.z; e6 = e6>0.f?e6:ALPHA*e6; float w6 = a1.z>0?__expf(e6):0.f;
    float e7 = f1v + g1.w; e7 = e7>0.f?e7:ALPHA*e7; float w7 = a1.w>0?__expf(e7):0.f;
    uint4 pk;
    pk.x = f2bf(w0) | (f2bf(w1) << 16);
    pk.y = f2bf(w2) | (f2bf(w3) << 16);
    pk.z = f2bf(w4) | (f2bf(w5) << 16);
    pk.w = f2bf(w6) | (f2bf(w7) << 16);
    short8 af = __builtin_bit_cast(short8, pk);
    #pragma unroll
    for(int t=0;t<8;t++) den += bf2f(af[t]);   // identical numerics to LDS version
    // ---- MFMA ----
    #pragma unroll
    for(int c=0;c<8;c++)
      acc[c] = __builtin_amdgcn_mfma_f32_16x16x32_bf16(af, bf[c], acc[c], 0,0,0);
    a0 = na0; a1 = na1; g0 = ng0; g1 = ng1;
  }

  // den: lanes m, m+16, m+32, m+48 hold q-partials of row m
  den += __shfl_down(den, 32); den += __shfl_down(den, 16);
  if(lane < 16) denp[(size_t)jc*N_NODES + r0w + lane] = den;
  // C/D layout: col = c*16 + m, row = q*4 + reg (verified)
  float* pp = part + (size_t)jc*N_NODES*OUT_F;
  #pragma unroll
  for(int c=0;c<8;c++){
    #pragma unroll
    for(int reg=0;reg<4;reg++)
      pp[(size_t)(r0w + q*4 + reg)*OUT_F + c*16 + m] = acc[c][reg];
  }
}

// ---------------- K2: out = elu(sum(parts)/sum(dens)), float4 ----------------
__global__ __launch_bounds__(256) void k_out(const float* __restrict__ part,
    const float* __restrict__ denp, float* __restrict__ out){
  const int idx = blockIdx.x*256 + threadIdx.x;    // float4 index
  const int r = idx >> 5;                          // (idx*4) >> 7
  float4 v = {0.f,0.f,0.f,0.f};
  float d = 0.f;
  #pragma unroll
  for(int p=0;p<JC;p++){
    float4 pv = *((const float4*)part + (size_t)p*(N_NODES*OUT_F/4) + idx);
    v.x += pv.x; v.y += pv.y; v.z += pv.z; v.w += pv.w;
    d += denp[(size_t)p*N_NODES + r];
  }
  float4 o;
  o.x = v.x/d; o.y = v.y/d; o.z = v.z/d; o.w = v.w/d;
  o.x = o.x>0.f ? o.x : (__expf(o.x)-1.f);
  o.y = o.y>0.f ? o.y : (__expf(o.y)-1.f);
  o.z = o.z>0.f ? o.z : (__expf(o.z)-1.f);
  o.w = o.w>0.f ? o.w : (__expf(o.w)-1.f);
  *((float4*)out + idx) = o;
}

extern "C" void kernel_launch(void* const* d_in, const int* in_sizes, int n_in,
                              void* d_out, int out_size, void* d_ws, size_t ws_size,
                              hipStream_t stream){
  const float* x   = (const float*)d_in[0];
  const int*   adj = (const int*)d_in[1];
  const float* W   = (const float*)d_in[2];
  const float* a   = (const float*)d_in[3];
  char* ws = (char*)d_ws;
  unsigned short* P = (unsigned short*)ws;                 // 2 MiB
  float* f1         = (float*)(ws + (2u<<20));             // 32 KiB
  float* f2         = (float*)(ws + (2u<<20) + (32u<<10)); // 32 KiB
  float* part       = (float*)(ws + (4u<<20));             // 16 MiB
  float* denp       = (float*)(ws + (20u<<20));            // 128 KiB
  float* out        = (float*)d_out;

  k_hfp<<<512, 256, 0, stream>>>(x, W, a, P, f1, f2);
  k_attn<<<dim3(JC,128), 256, 0, stream>>>(adj, P, f1, f2, part, denp);
  k_out<<<(N_NODES*OUT_F)/4/256, 256, 0, stream>>>(part, denp, out);
}

// Round 4
// 400.202 us; speedup vs baseline: 1.4396x; 1.4396x over previous
//
#include <hip/hip_runtime.h>

#define N_NODES 8192
#define IN_F 256
#define OUT_F 128
#define ALPHA 0.5f
#define JC 8
#define KCHUNK 1024            // N_NODES / JC
#define RK 128                 // k-window per round
#define ROUNDS 8               // KCHUNK / RK
#define RSTEPS 4               // 32-k MFMA steps per round

using short8 = __attribute__((ext_vector_type(8))) short;
using f32x4  = __attribute__((ext_vector_type(4))) float;

__device__ __forceinline__ unsigned int f2bf(float f){
  unsigned int u = __float_as_uint(f);
  u += 0x7fffu + ((u >> 16) & 1u);   // RNE
  return u >> 16;
}
__device__ __forceinline__ float bf2f(short s){
  return __uint_as_float(((unsigned int)(unsigned short)s) << 16);
}

// ---------------- K0: fused  h = x@W  ->  {f1, f2, P(bf16 frag-major)} -----
// h is never written to global: f1/f2 reduced from fp32 accumulators,
// bf16 pack done via LDS re-stage (reusing the x staging buffer).
__global__ __launch_bounds__(256) void k_hfp(const float* __restrict__ x,
                                             const float* __restrict__ W,
                                             const float* __restrict__ a,
                                             unsigned short* __restrict__ P,
                                             float* __restrict__ f1,
                                             float* __restrict__ f2){
  __shared__ float xs[16*IN_F];            // 16 KB; reused as hs[16][132]
  const int tid = threadIdx.x;
  const int bx = blockIdx.x;
  const int r0 = bx * 16;
  const float4* xg = (const float4*)(x + (size_t)r0*IN_F);
  float4* xl = (float4*)xs;
  #pragma unroll
  for(int i=0;i<4;i++) xl[tid + i*256] = xg[tid + i*256];
  __syncthreads();
  const int wave = tid >> 6, lane = tid & 63;
  float2 acc[4];
  #pragma unroll
  for(int j=0;j<4;j++){ acc[j].x = 0.f; acc[j].y = 0.f; }
  const float2* Wp = (const float2*)W;
  for(int k4=0;k4<IN_F;k4+=4){
    float4 xq[4];
    #pragma unroll
    for(int j=0;j<4;j++) xq[j] = *(const float4*)&xs[(wave*4+j)*IN_F + k4];
    #pragma unroll
    for(int kk=0;kk<4;kk++){
      float2 wv = Wp[(size_t)(k4+kk)*64 + lane];
      #pragma unroll
      for(int j=0;j<4;j++){
        float xv = kk==0?xq[j].x : kk==1?xq[j].y : kk==2?xq[j].z : xq[j].w;
        acc[j].x += xv*wv.x; acc[j].y += xv*wv.y;
      }
    }
  }
  // ---- f1 = h@a1, f2 = h@a2 from fp32 accumulators ----
  float2 av1 = ((const float2*)a)[lane];
  float2 av2 = ((const float2*)(a + OUT_F))[lane];
  #pragma unroll
  for(int j=0;j<4;j++){
    float s1 = acc[j].x*av1.x + acc[j].y*av1.y;
    float s2 = acc[j].x*av2.x + acc[j].y*av2.y;
    #pragma unroll
    for(int off=32; off; off>>=1){
      s1 += __shfl_down(s1, off);
      s2 += __shfl_down(s2, off);
    }
    if(lane == 0){ f1[r0 + wave*4 + j] = s1; f2[r0 + wave*4 + j] = s2; }
  }
  // ---- pack bf16 fragment-major into P via LDS re-stage ----
  // P short idx ((kb*8+c)*64 + q*16 + n)*8 + t = bf16(h[kb*32+q*8+t][c*16+n])
  __syncthreads();                         // all waves done reading xs
  #pragma unroll
  for(int j=0;j<4;j++) *(float2*)&xs[(wave*4+j)*132 + lane*2] = acc[j];
  __syncthreads();
  const int kb = bx >> 1, half = bx & 1;   // this block = rows [r0, r0+16) = half of kb's 32
  const int c = tid >> 5, ql = (tid >> 4) & 1, n = tid & 15;
  short8 v;
  #pragma unroll
  for(int t=0;t<8;t++) v[t] = (short)f2bf(xs[(ql*8+t)*132 + c*16 + n]);
  *(short8*)(P + ((size_t)((kb*8 + c)*64 + half*32 + ql*16 + n))*8) = v;
}

// ---------------- K1: fused masked-exp + attn@h -> per-chunk partials ------
// grid (JC=8, 128) x 256 thr. 64-row x 1024-col blocks, LDS 48.5 KB ->
// 3 blocks/CU co-resident (launch_bounds(256,3)): while one block sits in
// its barrier vmcnt-drain, the other two keep the adj HBM stream flowing.
// Staging: adj int4 loads interleaved IN the exp/pack loop (proven round-2
// structure — latency overlaps the VALU work of earlier iterations).
__global__ __launch_bounds__(256, 3) void k_attn(const int* __restrict__ adj,
    const unsigned short* __restrict__ P,
    const float* __restrict__ f1, const float* __restrict__ f2,
    float* __restrict__ part, float* __restrict__ denp){
  __shared__ __align__(16) unsigned short Alds[64*RK];   // 16 KB swizzled [row][k]
  __shared__ __align__(16) short Blds[RK*OUT_F];         // 32 KB fragment-major
  __shared__ float f1s[64];
  const int tid = threadIdx.x;
  const int wave = tid >> 6, lane = tid & 63;
  const int m = lane & 15, q = lane >> 4;
  const int jc = blockIdx.x;                 // linear id % 8 -> one jc per XCD
  const int r0b = blockIdx.y * 64;
  const int jb = jc * KCHUNK;
  const int kb0 = jc * (KCHUNK/32);
  // staging coords: thread covers rows {i*8+srow}, k-cols [sc0, sc0+4)
  const int srow = tid >> 5;                 // 0..7
  const int sc0  = (tid & 31) * 4;           // 0..124
  const int swz  = ((((sc0 >> 3) ^ srow) << 4) | ((sc0 & 4) << 1));

  if(tid < 64) f1s[tid] = f1[r0b + tid];

  f32x4 acc0[8];
  #pragma unroll
  for(int c=0;c<8;c++) acc0[c] = (f32x4){0,0,0,0};
  float den0 = 0.f;

  const char* Ab = (const char*)Alds;
  char* Aw = (char*)Alds + swz;
  const int mw = m & 7;
  const int rg0 = wave*16 + m;

  __syncthreads();                           // f1s ready

  for(int rd=0; rd<ROUNDS; rd++){
    const int kbase = jb + rd*RK;
    // ---- B-tile: 32KB linear memcpy from P (L2-resident per XCD) ----
    const int4* Pb = (const int4*)(P + ((size_t)(kb0 + rd*4) << 12));
    int4* Bl4 = (int4*)Blds;
    #pragma unroll
    for(int i=0;i<8;i++) Bl4[i*256 + tid] = Pb[i*256 + tid];
    // ---- A-tile: linear adj read -> w -> swizzled LDS ----
    float4 fv = *(const float4*)(f2 + kbase + sc0);
    const char* ap = (const char*)adj + (((size_t)(r0b + srow)*N_NODES + kbase + sc0) << 2);
    #pragma unroll
    for(int i=0;i<8;i++){
      int4 av = *(const int4*)(ap + ((size_t)i*8*N_NODES << 2));
      float f1v = f1s[i*8 + srow];
      float t0 = f1v + fv.x, t1 = f1v + fv.y, t2 = f1v + fv.z, t3 = f1v + fv.w;
      t0 = t0 > 0.f ? t0 : ALPHA*t0;  t1 = t1 > 0.f ? t1 : ALPHA*t1;
      t2 = t2 > 0.f ? t2 : ALPHA*t2;  t3 = t3 > 0.f ? t3 : ALPHA*t3;
      float w0 = av.x > 0 ? __expf(t0) : 0.f;
      float w1 = av.y > 0 ? __expf(t1) : 0.f;
      float w2 = av.z > 0 ? __expf(t2) : 0.f;
      float w3 = av.w > 0 ? __expf(t3) : 0.f;
      uint2 pk;
      pk.x = f2bf(w0) | (f2bf(w1) << 16);
      pk.y = f2bf(w2) | (f2bf(w3) << 16);
      *(uint2*)(Aw + (i*8 + srow)*(RK*2)) = pk;
    }
    __syncthreads();
    // ---- MFMA phase: LDS only ----
    #pragma unroll
    for(int s=0;s<RSTEPS;s++){
      const int gq = ((s*4 + q) ^ mw) << 4;
      short8 A0 = *(const short8*)(Ab + rg0*(RK*2) + gq);
      #pragma unroll
      for(int t=0;t<8;t++) den0 += bf2f(A0[t]);
      const short8* Bl = (const short8*)Blds + s*512 + lane;
      #pragma unroll
      for(int c=0;c<8;c++){
        short8 Bf = Bl[c*64];
        acc0[c] = __builtin_amdgcn_mfma_f32_16x16x32_bf16(A0, Bf, acc0[c], 0,0,0);
      }
    }
    __syncthreads();
  }

  // den: lanes m, m+16, m+32, m+48 hold q-partials of row m
  den0 += __shfl_down(den0, 32); den0 += __shfl_down(den0, 16);
  const int r0w = r0b + wave*16;
  if(lane < 16) denp[(size_t)jc*N_NODES + r0w + lane] = den0;
  // C/D layout: col = c*16 + m, row = q*4 + reg (verified)
  float* pp = part + (size_t)jc*N_NODES*OUT_F;
  #pragma unroll
  for(int c=0;c<8;c++){
    #pragma unroll
    for(int reg=0;reg<4;reg++)
      pp[(size_t)(r0w + q*4 + reg)*OUT_F + c*16 + m] = acc0[c][reg];
  }
}

// ---------------- K2: out = elu(sum(parts)/sum(dens)), float4 ----------------
__global__ __launch_bounds__(256) void k_out(const float* __restrict__ part,
    const float* __restrict__ denp, float* __restrict__ out){
  const int idx = blockIdx.x*256 + threadIdx.x;    // float4 index
  const int r = idx >> 5;                          // (idx*4) >> 7
  float4 v = {0.f,0.f,0.f,0.f};
  float d = 0.f;
  #pragma unroll
  for(int p=0;p<JC;p++){
    float4 pv = *((const float4*)part + (size_t)p*(N_NODES*OUT_F/4) + idx);
    v.x += pv.x; v.y += pv.y; v.z += pv.z; v.w += pv.w;
    d += denp[(size_t)p*N_NODES + r];
  }
  float4 o;
  o.x = v.x/d; o.y = v.y/d; o.z = v.z/d; o.w = v.w/d;
  o.x = o.x>0.f ? o.x : (__expf(o.x)-1.f);
  o.y = o.y>0.f ? o.y : (__expf(o.y)-1.f);
  o.z = o.z>0.f ? o.z : (__expf(o.z)-1.f);
  o.w = o.w>0.f ? o.w : (__expf(o.w)-1.f);
  *((float4*)out + idx) = o;
}

extern "C" void kernel_launch(void* const* d_in, const int* in_sizes, int n_in,
                              void* d_out, int out_size, void* d_ws, size_t ws_size,
                              hipStream_t stream){
  const float* x   = (const float*)d_in[0];
  const int*   adj = (const int*)d_in[1];
  const float* W   = (const float*)d_in[2];
  const float* a   = (const float*)d_in[3];
  char* ws = (char*)d_ws;
  unsigned short* P = (unsigned short*)ws;                 // 2 MiB
  float* f1         = (float*)(ws + (2u<<20));             // 32 KiB
  float* f2         = (float*)(ws + (2u<<20) + (32u<<10)); // 32 KiB
  float* part       = (float*)(ws + (4u<<20));             // 32 MiB
  float* denp       = (float*)(ws + (36u<<20));            // 256 KiB
  float* out        = (float*)d_out;

  k_hfp<<<512, 256, 0, stream>>>(x, W, a, P, f1, f2);
  k_attn<<<dim3(JC,128), 256, 0, stream>>>(adj, P, f1, f2, part, denp);
  k_out<<<(N_NODES*OUT_F)/4/256, 256, 0, stream>>>(part, denp, out);
}